// Round 6
// baseline (390.186 us; speedup 1.0000x reference)
//
#include <hip/hip_runtime.h>

typedef unsigned short u16;
typedef __attribute__((ext_vector_type(4))) float f32x4;
typedef __attribute__((ext_vector_type(8))) short s16x8;
typedef __attribute__((ext_vector_type(4))) unsigned short u16x4;

#define MFMA16(a, b, c) __builtin_amdgcn_mfma_f32_16x16x32_bf16((a), (b), (c), 0, 0, 0)

__device__ __forceinline__ u16 f2bf(float f) {
  union { float f; unsigned u; } v; v.f = f;
  unsigned u = v.u;
  u += 0x7fffu + ((u >> 16) & 1u);   // RNE
  return (u16)(u >> 16);
}

__device__ __forceinline__ void gl_lds16(const void* g, void* l) {
  __builtin_amdgcn_global_load_lds(
      (const __attribute__((address_space(1))) void*)g,
      (__attribute__((address_space(3))) void*)l, 16, 0, 0);
}

// Barrier with EXPLICIT async-LDS drain: global_load_lds completion is tracked
// by vmcnt; staged data is only safe to read after a vmcnt(0) drain + barrier.
// Do not rely on the compiler emitting the drain for address-space(3) stores
// it can't alias-track.
__device__ __forceinline__ void barrier_drain() {
  asm volatile("s_waitcnt vmcnt(0) lgkmcnt(0)" ::: "memory");
  __syncthreads();
}

// ---------------- fused cast fp32 -> bf16 ----------------
__global__ void cast6(const float* __restrict__ x,
                      const float* __restrict__ w0, const float* __restrict__ w1,
                      const float* __restrict__ w2, const float* __restrict__ w3,
                      u16* __restrict__ ws) {
  const int y = blockIdx.y;
  const float* src;
  u16* dst;
  if (y < 2) { src = x + (size_t)y * 4194304; dst = ws + (size_t)y * 4194304; }
  else {
    src = (y == 2) ? w0 : (y == 3) ? w1 : (y == 4) ? w2 : w3;
    dst = ws + 8388608 + (size_t)(y - 2) * 4194304;
  }
  const int i = blockIdx.x * 256 + threadIdx.x;
  f32x4 v = ((const f32x4*)src)[i];
  u16x4 o;
#pragma unroll
  for (int e = 0; e < 4; ++e) o[e] = f2bf(v[e]);
  ((u16x4*)dst)[i] = o;
}

// ---------------- shared GEMM K-loop core (888 TF plateau — done) ----------------
template <int SWAP>
__device__ __forceinline__ void gemm_core(const u16* __restrict__ A,
                                          const u16* __restrict__ Bw,
                                          u16* sA, u16* sB,
                                          f32x4 (&acc)[4][4],
                                          int m0, int n0, int tid) {
  const int lane = tid & 63, w = tid >> 6;
  const int ln = lane & 15, quad = lane >> 4, ln7 = ln & 7;
  const int wm = (w >> 1) * 64, wn = (w & 1) * 64;
  const int srow = lane >> 3;                       // 0..7 = row&7 of staged row
  const int scol = (((lane & 7) ^ srow)) * 8;       // swizzled source column

  for (int k0 = 0; k0 < 2048; k0 += 64) {
#pragma unroll
    for (int c = 0; c < 4; ++c) {
      const int chunk = c * 4 + w;
      const int row = chunk * 8 + srow;
      gl_lds16(A + (size_t)(m0 + row) * 2048 + k0 + scol, (char*)sA + chunk * 1024);
      gl_lds16(Bw + (size_t)(n0 + row) * 2048 + k0 + scol, (char*)sB + chunk * 1024);
    }
    __syncthreads();
#pragma unroll
    for (int kk = 0; kk < 64; kk += 32) {
      s16x8 af[4], bf[4];
      const int g = (kk >> 3) + quad;
#pragma unroll
      for (int t = 0; t < 4; ++t) {
        af[t] = *(const s16x8*)&sA[(wm + t * 16 + ln) * 64 + ((g ^ ln7) << 3)];
        bf[t] = *(const s16x8*)&sB[(wn + t * 16 + ln) * 64 + ((g ^ ln7) << 3)];
      }
#pragma unroll
      for (int tm = 0; tm < 4; ++tm)
#pragma unroll
        for (int tn = 0; tn < 4; ++tn)
          acc[tm][tn] = SWAP ? MFMA16(bf[tn], af[tm], acc[tm][tn])
                             : MFMA16(af[tm], bf[tn], acc[tm][tn]);
    }
    __syncthreads();
  }
}

// ---------------- fused Q/K/V projection GEMMs ----------------
__global__ __launch_bounds__(256, 2) void gemm_qkv(
    const u16* __restrict__ A,
    const u16* __restrict__ W0, const u16* __restrict__ W1, const u16* __restrict__ W2,
    const float* __restrict__ b0, const float* __restrict__ b1, const float* __restrict__ b2,
    u16* __restrict__ Qo, u16* __restrict__ Ko, u16* __restrict__ Vo) {
  __shared__ __align__(16) u16 smem[16384];
  u16* sA = smem;
  u16* sB = smem + 8192;
  const int z = blockIdx.z;
  const u16* Bw = (z == 0) ? W0 : (z == 1) ? W1 : W2;
  const float* bias = (z == 0) ? b0 : (z == 1) ? b1 : b2;

  const int tid = threadIdx.x;
  const int lane = tid & 63, w = tid >> 6;
  const int ln = lane & 15, quad = lane >> 4;
  const int m0 = blockIdx.y * 128, n0 = blockIdx.x * 128;
  const int wm = (w >> 1) * 64, wn = (w & 1) * 64;

  f32x4 acc[4][4] = {};
  if (z < 2) {
    gemm_core<1>(A, Bw, sA, sB, acc, m0, n0, tid);
    u16* out = (z == 0) ? Qo : Ko;
    const float scale = (z == 0) ? 0.08838834764831845f : 1.0f;
#pragma unroll
    for (int tn = 0; tn < 4; ++tn) {
      const int n_base = n0 + wn + tn * 16 + quad * 4;
      const f32x4 bv = *(const f32x4*)&bias[n_base];
      const int h = n_base >> 7, dl = n_base & 127;
#pragma unroll
      for (int tm = 0; tm < 4; ++tm) {
        const int m = m0 + wm + tm * 16 + ln;
        const int b = m >> 11, s = m & 2047;
        u16x4 ov;
#pragma unroll
        for (int r = 0; r < 4; ++r) ov[r] = f2bf((acc[tm][tn][r] + bv[r]) * scale);
        *(u16x4*)&out[(((size_t)(b * 16 + h)) << 18) + ((size_t)s << 7) + dl] = ov;
      }
    }
  } else {
    gemm_core<0>(A, Bw, sA, sB, acc, m0, n0, tid);
    const int b = m0 >> 11;
#pragma unroll
    for (int tn = 0; tn < 4; ++tn) {
      const int n = n0 + wn + tn * 16 + ln;   // global d index
      const float bv = bias[n];
      const int h = n >> 7, dl = n & 127;
#pragma unroll
      for (int tm = 0; tm < 4; ++tm) {
        const int s_base = (m0 & 2047) + wm + tm * 16 + quad * 4;
        u16x4 ov;
#pragma unroll
        for (int r = 0; r < 4; ++r) ov[r] = f2bf(acc[tm][tn][r] + bv);
        *(u16x4*)&Vo[(((size_t)((b * 16 + h) * 128 + dl)) << 11) + s_base] = ov;
      }
    }
  }
}

// ---------------- output projection GEMM (fp32 out) ----------------
__global__ __launch_bounds__(256, 2) void gemm_out(const u16* __restrict__ A,
                                                   const u16* __restrict__ Bw,
                                                   const float* __restrict__ bias,
                                                   float* __restrict__ out) {
  __shared__ __align__(16) u16 smem[16384];
  u16* sA = smem;
  u16* sB = smem + 8192;
  const int tid = threadIdx.x;
  const int lane = tid & 63, w = tid >> 6;
  const int ln = lane & 15, quad = lane >> 4;
  const int m0 = blockIdx.y * 128, n0 = blockIdx.x * 128;
  const int wm = (w >> 1) * 64, wn = (w & 1) * 64;

  f32x4 acc[4][4] = {};
  gemm_core<1>(A, Bw, sA, sB, acc, m0, n0, tid);
#pragma unroll
  for (int tn = 0; tn < 4; ++tn) {
    const int n_base = n0 + wn + tn * 16 + quad * 4;
    const f32x4 bv = *(const f32x4*)&bias[n_base];
#pragma unroll
    for (int tm = 0; tm < 4; ++tm) {
      const int m = m0 + wm + tm * 16 + ln;
      f32x4 ov;
#pragma unroll
      for (int r = 0; r < 4; ++r) ov[r] = acc[tm][tn][r] + bv[r];
      *(f32x4*)&out[(size_t)m * 2048 + n_base] = ov;
    }
  }
}

// ---------------- causal flash attention (S^T, Q-tile 64, 4 blocks/CU) ----------------
// Q,K: [B,H,S,D] bf16 (Q pre-scaled); Vt: [B,H,D,S] bf16. ctx: [B,S,E] bf16.
// LDS 40KB (sP 8K | sK 16K | sV 16K) -> 4 blocks/CU. Every barrier uses an
// explicit vmcnt drain (barrier_drain) so staged global_load_lds data is
// guaranteed visible — do not rely on compiler waitcnt insertion here.
__global__ __launch_bounds__(256, 4) void attn_kernel(const u16* __restrict__ Q,
                                                      const u16* __restrict__ Kp,
                                                      const u16* __restrict__ Vt,
                                                      u16* __restrict__ ctx) {
  __shared__ __align__(16) u16 smem[20480];  // u16 counts: sP 4096 | sK 8192 | sV 8192
  u16* sP = smem;
  u16* sK = smem + 4096;
  u16* sV = smem + 12288;

  const int f = blockIdx.x;
  const int i = (f & 1) ? (f >> 1) : (31 - (f >> 1));  // zigzag: 31,0,30,1,...
  const int bh = blockIdx.y;
  const size_t base = (size_t)bh << 18;

  const int tid = threadIdx.x, lane = tid & 63, w = tid >> 6;
  const int ln = lane & 15, quad = lane >> 4, ln7 = lane & 7;

  // ---- stage Q tile (64 rows x 128 d = 16KB) into sK, swizzled ----
#pragma unroll
  for (int c = 0; c < 4; ++c) {
    const int chunk0 = (c * 4 + w) * 64;
    const int chunk = chunk0 + lane;
    const int row = chunk >> 4, cc = chunk & 15;
    gl_lds16(Q + base + (size_t)((i * 64 + row) * 128 + ((cc ^ (row & 15)) << 3)),
             (char*)sK + chunk0 * 16);
  }
  barrier_drain();
  s16x8 qf[4];
#pragma unroll
  for (int kc = 0; kc < 4; ++kc)
    qf[kc] = *(const s16x8*)&sK[(w * 16 + ln) * 128 + (((kc * 4 + quad) ^ ln) << 3)];
  barrier_drain();

  auto stageK = [&](int j) {
#pragma unroll
    for (int c = 0; c < 4; ++c) {
      const int chunk0 = (c * 4 + w) * 64;
      const int chunk = chunk0 + lane;
      const int row = chunk >> 4, cc = chunk & 15;
      gl_lds16(Kp + base + (size_t)((j * 64 + row) * 128 + ((cc ^ (row & 15)) << 3)),
               (char*)sK + chunk0 * 16);
    }
  };
  auto stageV = [&](int j) {
#pragma unroll
    for (int c = 0; c < 4; ++c) {
      const int chunk0 = (c * 4 + w) * 64;
      const int chunk = chunk0 + lane;
      const int row = chunk >> 3, cc = chunk & 7;
      gl_lds16(Vt + base + (size_t)(row * 2048 + j * 64 + ((cc ^ (row & 7)) << 3)),
               (char*)sV + chunk0 * 16);
    }
  };

  stageK(0);
  stageV(0);
  barrier_drain();

  f32x4 o_acc[8] = {};
  float lsum = 0.f;
  const int qg = i * 64 + w * 16 + ln;  // lane's global q row

  for (int j = 0; j <= i; ++j) {
    // ---- S^T = K . Q^T (64k x 64q): A = K frags, B = Q regs ----
    f32x4 sacc[4] = {};
#pragma unroll
    for (int kc = 0; kc < 4; ++kc) {
      s16x8 kf[4];
#pragma unroll
      for (int kt = 0; kt < 4; ++kt)
        kf[kt] = *(const s16x8*)&sK[(kt * 16 + ln) * 128 + (((kc * 4 + quad) ^ ln) << 3)];
#pragma unroll
      for (int kt = 0; kt < 4; ++kt)
        sacc[kt] = MFMA16(kf[kt], qf[kc], sacc[kt]);
    }

    // ---- exp + mask (diag iter only) + pack P[q][k] via b64 writes ----
    const bool diag = (j == i);
    const int qrow = w * 16 + ln;
#pragma unroll
    for (int kt = 0; kt < 4; ++kt) {
      u16x4 pk;
#pragma unroll
      for (int r = 0; r < 4; ++r) {
        float pv = __expf(sacc[kt][r]);
        if (diag) {
          const int kg = j * 64 + kt * 16 + quad * 4 + r;
          if (kg > qg) pv = 0.f;
        }
        lsum += pv;
        pk[r] = f2bf(pv);
      }
      const int c = kt * 4 + quad;
      *(u16x4*)&sP[qrow * 64 + ((c ^ (qrow & 14)) << 2)] = pk;
    }
    barrier_drain();            // A: QK sK reads done; V(j) staged; P visible
    if (j < i) stageK(j + 1);   // overlaps PV

    // ---- O^T += V . P^T : A = V frags (d rows), B = P frags (q rows) ----
#pragma unroll
    for (int kc = 0; kc < 2; ++kc) {
      const int c0 = kc * 8 + quad * 2;
      s16x8 pf = *(const s16x8*)&sP[qrow * 64 + ((c0 ^ (qrow & 14)) << 2)];
#pragma unroll
      for (int dg = 0; dg < 2; ++dg) {   // split vf into 2 chunks of 4 (reg cap)
        s16x8 vf[4];
#pragma unroll
        for (int t = 0; t < 4; ++t)
          vf[t] = *(const s16x8*)&sV[((dg * 4 + t) * 16 + ln) * 64 +
                                     (((kc * 4 + quad) ^ ln7) << 3)];
#pragma unroll
        for (int t = 0; t < 4; ++t)
          o_acc[dg * 4 + t] = MFMA16(vf[t], pf, o_acc[dg * 4 + t]);
      }
    }
    barrier_drain();            // B: PV sV/sP reads done; K(j+1) staged
    if (j < i) stageV(j + 1);   // overlaps next QK+exp
  }

  // ---- epilogue: reduce lsum over quads, scale, u16x4 ctx stores ----
  const int b = bh >> 4, h = bh & 15;
  float s = lsum;
  s += __shfl_xor(s, 16);
  s += __shfl_xor(s, 32);
  const float rinv = __builtin_amdgcn_rcpf(s);
  const int sg = i * 64 + w * 16 + ln;
#pragma unroll
  for (int dt = 0; dt < 8; ++dt) {
    const int d0 = h * 128 + dt * 16 + quad * 4;
    u16x4 ov;
#pragma unroll
    for (int r = 0; r < 4; ++r) ov[r] = f2bf(o_acc[dt][r] * rinv);
    *(u16x4*)&ctx[((size_t)b << 22) + (size_t)sg * 2048 + d0] = ov;
  }
}

// ---------------- launch ----------------
extern "C" void kernel_launch(void* const* d_in, const int* in_sizes, int n_in,
                              void* d_out, int out_size, void* d_ws, size_t ws_size,
                              hipStream_t stream) {
  const float* x = (const float*)d_in[0];
  const float* Wq = (const float*)d_in[1];
  const float* bq = (const float*)d_in[2];
  const float* Wk = (const float*)d_in[3];
  const float* bk = (const float*)d_in[4];
  const float* Wv = (const float*)d_in[5];
  const float* bv = (const float*)d_in[6];
  const float* Wo = (const float*)d_in[7];
  const float* bo = (const float*)d_in[8];

  u16* ws = (u16*)d_ws;
  u16* xb = ws;
  u16* Wqb = xb + 8388608;
  u16* Wkb = Wqb + 4194304;
  u16* Wvb = Wkb + 4194304;
  u16* Wob = Wvb + 4194304;
  u16* Qb = Wob + 4194304;    // [B,H,S,D] (pre-scaled)
  u16* Kb = Qb + 8388608;     // [B,H,S,D]
  u16* Vtb = Kb + 8388608;    // [B,H,D,S]
  u16* ctxb = Vtb + 8388608;  // [B,S,E]

  cast6<<<dim3(4096, 6), 256, 0, stream>>>(x, Wq, Wk, Wv, Wo, ws);

  gemm_qkv<<<dim3(16, 32, 3), 256, 0, stream>>>(xb, Wqb, Wkb, Wvb, bq, bk, bv, Qb, Kb, Vtb);

  attn_kernel<<<dim3(32, 32), 256, 0, stream>>>(Qb, Kb, Vtb, ctxb);

  gemm_out<<<dim3(16, 32), 256, 0, stream>>>(ctxb, Wob, bo, (float*)d_out);
}